// Round 10
// baseline (2739.647 us; speedup 1.0000x reference)
//
#include <hip/hip_runtime.h>
#include <stdint.h>

// ---- problem constants -----------------------------------------------------
#define N_TOK   8192
#define DIMK    1024      // D == H == 1024
#define NEXP    8
#define PADROWS 17408     // 16384 assignments + up to 8*128 padding, 128-aligned
#define MAXRT   136       // max row tiles of 128

typedef __attribute__((ext_vector_type(8))) short short8;   // 8 bf16 (4 VGPRs)
typedef __attribute__((ext_vector_type(4))) float f32x4;    // MFMA accumulator
typedef unsigned short u16;

__device__ __forceinline__ u16 f2bf(float f) {              // RNE f32->bf16
  uint32_t u = __builtin_bit_cast(uint32_t, f);
  u += 0x7fffu + ((u >> 16) & 1u);
  return (u16)(u >> 16);
}

__device__ __forceinline__ void load16_lds(const void* g, void* l) {
  __builtin_amdgcn_global_load_lds(
      (const __attribute__((address_space(1))) void*)g,
      (__attribute__((address_space(3))) void*)l, 16, 0, 0);
}

// ---- workspace layout (bytes) ----------------------------------------------
#define OFF_W1T   0u
#define OFF_W2T   16777216u
#define OFF_XP    33554432u
#define OFF_H1    69206016u
#define OFF_GIDX  104857600u
#define OFF_GVAL  104923136u
#define OFF_PTOK  104988672u
#define OFF_PGATE 105058304u
#define OFF_CTRL  105127936u
// zero region each launch: ptok + pgate + ctrl = 69632+69632+128 = 139392 B

// ---- W transpose+convert via LDS tile: WT[e][n][k] = bf16(W[e][k][n]) ------
__global__ void convw_kernel(const float* __restrict__ W1, const float* __restrict__ W2,
                             u16* __restrict__ W1T, u16* __restrict__ W2T) {
  __shared__ u16 tile[64][65];
  int b = (int)blockIdx.x;
  const float* src = W1; u16* dst = W1T;
  if (b >= 2048) { src = W2; dst = W2T; b -= 2048; }
  const int e  = b >> 8;
  const int t  = b & 255;
  const int k0 = (t >> 4) << 6;
  const int n0 = (t & 15) << 6;
  const int tid = (int)threadIdx.x;
  const int r  = tid >> 2;
  const int c4 = (tid & 3) << 4;
  const float4* s = (const float4*)(src + ((size_t)e << 20) +
                                    ((size_t)(k0 + r) << 10) + n0 + c4);
#pragma unroll
  for (int j = 0; j < 4; ++j) {
    float4 v = s[j];
    tile[r][c4 + 4 * j + 0] = f2bf(v.x);
    tile[r][c4 + 4 * j + 1] = f2bf(v.y);
    tile[r][c4 + 4 * j + 2] = f2bf(v.z);
    tile[r][c4 + 4 * j + 3] = f2bf(v.w);
  }
  __syncthreads();
  const int on = tid >> 2;
  const int ok = (tid & 3) << 4;
  u16* d = dst + ((size_t)e << 20) + ((size_t)(n0 + on) << 10) + k0 + ok;
  short8 v0, v1;
#pragma unroll
  for (int j = 0; j < 8; ++j) {
    v0[j] = (short)tile[ok + j][on];
    v1[j] = (short)tile[ok + 8 + j][on];
  }
  *(short8*)d = v0;
  *(short8*)(d + 8) = v1;
}

// ---- gating: f32 logits, top-2 (jax tie-break), softmax, histogram ---------
__global__ void gate_kernel(const float* __restrict__ x, const float* __restrict__ Wg,
                            const float* __restrict__ bg, int* __restrict__ gidx,
                            float* __restrict__ gval, int* __restrict__ counts) {
  __shared__ int hist[NEXP];
  const int tid = (int)threadIdx.x;
  if (tid < NEXP) hist[tid] = 0;
  __syncthreads();
  const int n = (int)blockIdx.x * 4 + (tid >> 6);
  const int lane = tid & 63;
  float acc[NEXP];
#pragma unroll
  for (int e = 0; e < NEXP; ++e) acc[e] = 0.f;
  const float4* xr = (const float4*)(x + ((size_t)n << 10));
#pragma unroll
  for (int j = 0; j < 4; ++j) {
    float4 xv = xr[j * 64 + lane];
#pragma unroll
    for (int e = 0; e < NEXP; ++e) {
      float4 wv = ((const float4*)(Wg + ((size_t)e << 10)))[j * 64 + lane];
      acc[e] += xv.x * wv.x + xv.y * wv.y + xv.z * wv.z + xv.w * wv.w;
    }
  }
#pragma unroll
  for (int e = 0; e < NEXP; ++e)
#pragma unroll
    for (int off = 32; off; off >>= 1) acc[e] += __shfl_xor(acc[e], off, 64);
  if (lane == 0) {
    float lg[NEXP];
#pragma unroll
    for (int e = 0; e < NEXP; ++e) lg[e] = acc[e] + bg[e];
    int e0 = 0; float v0 = lg[0];
#pragma unroll
    for (int e = 1; e < NEXP; ++e) if (lg[e] > v0) { v0 = lg[e]; e0 = e; }
    int e1 = -1; float v1 = -1e30f;
#pragma unroll
    for (int e = 0; e < NEXP; ++e) if (e != e0 && lg[e] > v1) { v1 = lg[e]; e1 = e; }
    float t = expf(v1 - v0);            // v0 >= v1
    float g0 = 1.f / (1.f + t);
    gidx[2 * n] = e0; gidx[2 * n + 1] = e1;
    gval[2 * n] = g0; gval[2 * n + 1] = t * g0;
    atomicAdd(&hist[e0], 1); atomicAdd(&hist[e1], 1);
  }
  __syncthreads();
  if (tid < NEXP && hist[tid]) atomicAdd(&counts[tid], hist[tid]);
}

// ---- scan: 128-aligned segment offsets -------------------------------------
__global__ void scan_kernel(const int* __restrict__ counts, int* __restrict__ poff) {
  if (threadIdx.x == 0) {
    int off = 0; poff[0] = 0;
    for (int e = 0; e < NEXP; ++e) { off += ((counts[e] + 127) >> 7) << 7; poff[e + 1] = off; }
  }
}

// ---- scatter assignments into expert segments ------------------------------
__global__ void scatter_kernel(const int* __restrict__ gidx, const float* __restrict__ gval,
                               const int* __restrict__ poff, int* __restrict__ cursor,
                               int* __restrict__ ptok, float* __restrict__ pgate) {
  const int n = (int)blockIdx.x * 256 + (int)threadIdx.x;
#pragma unroll
  for (int k = 0; k < 2; ++k) {
    const int e = gidx[2 * n + k];
    const int p = poff[e] + atomicAdd(&cursor[e], 1);
    ptok[p] = n;
    pgate[p] = gval[2 * n + k];
  }
}

// ---- gather x rows (permuted) -> bf16 --------------------------------------
__global__ void gather_kernel(const float* __restrict__ x, const int* __restrict__ ptok,
                              u16* __restrict__ xp) {
  const int p = (int)blockIdx.x * 4 + ((int)threadIdx.x >> 6);
  const int lane = (int)threadIdx.x & 63;
  const int tok = ptok[p];
  const float4* src = (const float4*)(x + ((size_t)tok << 10));
  ushort4* dst = (ushort4*)(xp + ((size_t)p << 10));
#pragma unroll
  for (int j = 0; j < 4; ++j) {
    float4 v = src[j * 64 + lane];
    ushort4 o; o.x = f2bf(v.x); o.y = f2bf(v.y); o.z = f2bf(v.z); o.w = f2bf(v.w);
    dst[j * 64 + lane] = o;
  }
}

// ---- shared STAGE/COMPUTE building blocks (R3 structure) --------------------
#define STAGE_(ABASE, BBASE, ADST, BDST, K0)                                   \
  {                                                                            \
    _Pragma("unroll")                                                          \
    for (int i_ = 0; i_ < 4; ++i_) {                                           \
      const int chunk_ = wid * 4 + i_;                                         \
      const int row_ = chunk_ * 8 + r_in;                                      \
      const int slotL_ = s_phys ^ (row_ & 7);                                  \
      const size_t goff_ = ((size_t)row_ << 10) + (size_t)((K0) + slotL_ * 8); \
      load16_lds((ABASE) + goff_, (ADST) + chunk_ * 512);                      \
      load16_lds((BBASE) + goff_, (BDST) + chunk_ * 512);                      \
    }                                                                          \
  }

#define DCOMPUTE(ASRC, BSRC)                                                   \
  {                                                                            \
    _Pragma("unroll")                                                          \
    for (int kk = 0; kk < 2; ++kk) {                                           \
      short8 af[4], bf_[4];                                                    \
      const int kslot = kk * 4 + (lane >> 4);                                  \
      _Pragma("unroll")                                                        \
      for (int mi = 0; mi < 4; ++mi) {                                         \
        const int m = wm + mi * 16 + (lane & 15);                              \
        af[mi] = *(const short8*)((const char*)(ASRC) + m * 128 +              \
                                  ((kslot ^ (m & 7)) << 4));                   \
      }                                                                        \
      _Pragma("unroll")                                                        \
      for (int ni = 0; ni < 4; ++ni) {                                         \
        const int n = wn + ni * 16 + (lane & 15);                              \
        bf_[ni] = *(const short8*)((const char*)(BSRC) + n * 128 +             \
                                   ((kslot ^ (n & 7)) << 4));                  \
      }                                                                        \
      _Pragma("unroll")                                                        \
      for (int mi = 0; mi < 4; ++mi)                                           \
        _Pragma("unroll")                                                      \
        for (int ni = 0; ni < 4; ++ni)                                         \
          acc[mi][ni] = __builtin_amdgcn_mfma_f32_16x16x32_bf16(               \
              af[mi], bf_[ni], acc[mi][ni], 0, 0, 0);                          \
    }                                                                          \
  }

// ---- grouped GEMM: R3 verbatim (best measured: 121 us/pass) -----------------
template <int PASS>
__global__ __launch_bounds__(256, 2)
void gemm_kernel(const u16* __restrict__ A, const u16* __restrict__ WT,
                 const float* __restrict__ bias, const int* __restrict__ poff,
                 const int* __restrict__ ptok, const float* __restrict__ pgate,
                 u16* __restrict__ Hout, float* __restrict__ Out,
                 int* __restrict__ qhead) {
  __shared__ u16 As[2][128 * 64];
  __shared__ u16 Bs[2][128 * 64];
  __shared__ int tokS[128];
  __shared__ float gateS[128];
  __shared__ int tileS;

  const int tid = (int)threadIdx.x;
  const int lane = tid & 63;
  const int wid = tid >> 6;
  const int wm = (wid >> 1) * 64;
  const int wn = (wid & 1) * 64;
  const int r_in = lane >> 3;     // row within 8-row chunk
  const int s_phys = lane & 7;    // physical 16B slot

  const int total = (poff[NEXP] >> 7) * 8;

  for (;;) {
    if (tid == 0) tileS = atomicAdd(qhead, 1);
    __syncthreads();                       // publish tileS; fence prev epilogue
    const int tile = tileS;
    if (tile >= total) break;
    const int rt = tile >> 3;
    const int ct = tile & 7;
    const int row0 = rt * 128;
    int e = 0;
    while (row0 >= poff[e + 1]) ++e;       // 128-aligned segments: no spanning

    const u16* Ab = A + ((size_t)row0 << 10);
    const u16* Bb = WT + ((size_t)e << 20) + ((size_t)(ct * 128) << 10);

    if (PASS == 2 && tid < 128) {
      tokS[tid] = ptok[row0 + tid];
      gateS[tid] = pgate[row0 + tid];
    }

    f32x4 acc[4][4] = {};

    STAGE_(Ab, Bb, &As[0][0], &Bs[0][0], 0)
#pragma unroll
    for (int t = 0; t < 16; ++t) {         // FULL unroll: const buffer indices
      if (t < 15) {
        STAGE_(Ab, Bb, &As[(t + 1) & 1][0], &Bs[(t + 1) & 1][0], (t + 1) * 64)
        asm volatile("s_waitcnt vmcnt(8)" ::: "memory");  // prev 8 landed
      } else {
        asm volatile("s_waitcnt vmcnt(0)" ::: "memory");
      }
      __builtin_amdgcn_s_barrier();        // all waves' buf[t&1] ready
      DCOMPUTE(&As[t & 1][0], &Bs[t & 1][0])
      asm volatile("s_waitcnt lgkmcnt(0)" ::: "memory");
      __builtin_amdgcn_s_barrier();        // reads done; buf may be rewritten
    }

    // epilogue: C/D layout col = lane&15, row = (lane>>4)*4 + j  [m89/m91]
    const float* bb = bias + (e << 10) + ct * 128;
    const int cbase = lane & 15;
    const int rbase = (lane >> 4) * 4;
#pragma unroll
    for (int ni = 0; ni < 4; ++ni) {
      const int col = wn + ni * 16 + cbase;
      const float bv = bb[col];
#pragma unroll
      for (int mi = 0; mi < 4; ++mi) {
        const int mb = wm + mi * 16 + rbase;
#pragma unroll
        for (int j = 0; j < 4; ++j) {
          float v = fmaxf(acc[mi][ni][j] + bv, 0.0f);
          if (PASS == 1) {
            Hout[((size_t)(row0 + mb + j) << 10) + (size_t)(ct * 128 + col)] = f2bf(v);
          } else {
            const int m = mb + j;   // pad rows: gate==0 -> adds exactly 0
            unsafeAtomicAdd(Out + ((size_t)tokS[m] << 10) + (size_t)(ct * 128 + col),
                            v * gateS[m]);
          }
        }
      }
    }
  }
}

// ---- DIAG control: R9's diag_full unchanged (cross-build control) -----------
__global__ __launch_bounds__(256, 2)
void diag_full(const u16* __restrict__ A, const u16* __restrict__ WT,
               u16* __restrict__ sink) {
  __shared__ u16 As[2][128 * 64];
  __shared__ u16 Bs[2][128 * 64];
  const int tid = (int)threadIdx.x;
  const int lane = tid & 63;
  const int wid = tid >> 6;
  const int wm = (wid >> 1) * 64;
  const int wn = (wid & 1) * 64;
  const int r_in = lane >> 3;
  const int s_phys = lane & 7;
  const int bid = (int)blockIdx.x;
  const u16* Ab = A + ((size_t)((bid & 63) << 7) << 10);
  const u16* Bb = WT + ((size_t)(bid & 7) << 20) +
                  ((size_t)(((bid >> 3) & 7) << 7) << 10);
  f32x4 acc[4][4] = {};

  STAGE_(Ab, Bb, &As[0][0], &Bs[0][0], 0)
#pragma unroll 2
  for (int t = 0; t < 256; ++t) {
    STAGE_(Ab, Bb, &As[(t + 1) & 1][0], &Bs[(t + 1) & 1][0], ((t + 1) & 15) * 64)
    asm volatile("s_waitcnt vmcnt(8)" ::: "memory");
    __builtin_amdgcn_s_barrier();
    DCOMPUTE(&As[t & 1][0], &Bs[t & 1][0])
    asm volatile("s_waitcnt lgkmcnt(0)" ::: "memory");
    __builtin_amdgcn_s_barrier();
  }
  asm volatile("s_waitcnt vmcnt(0)" ::: "memory");
  float s = 0.f;
#pragma unroll
  for (int mi = 0; mi < 4; ++mi)
#pragma unroll
    for (int ni = 0; ni < 4; ++ni)
#pragma unroll
      for (int j = 0; j < 4; ++j) s += acc[mi][ni][j];
  sink[(size_t)bid * 256 + tid] = f2bf(s);
}

// ---- DIAG boundary ablation: 16 tiles x 16 steps (same K-work as diag_full),
// identical resident reads; ONLY the per-tile boundary varies.
// V0: drain+refill skeleton.  V1: + PASS1-style scalar strided epilogue.
// V2: + queue atomic + poff walk.  V3: + LDS-transpose vectorized epilogue.
template <int V>
__global__ __launch_bounds__(256, 2)
void diagT(const u16* __restrict__ A, const u16* __restrict__ WT,
           const float* __restrict__ bias, const int* __restrict__ poff,
           u16* __restrict__ sink, u16* __restrict__ sink2, int* __restrict__ dq) {
  __shared__ u16 As[2][128 * 64];
  __shared__ u16 Bs[2][128 * 64];
  __shared__ int tS;
  const int tid = (int)threadIdx.x;
  const int lane = tid & 63;
  const int wid = tid >> 6;
  const int wm = (wid >> 1) * 64;
  const int wn = (wid & 1) * 64;
  const int r_in = lane >> 3;
  const int s_phys = lane & 7;
  const int bid = (int)blockIdx.x;
  const u16* Ab = A + ((size_t)((bid & 63) << 7) << 10);
  const u16* Bb = WT + ((size_t)(bid & 7) << 20) +
                  ((size_t)(((bid >> 3) & 7) << 7) << 10);

#pragma unroll 1
  for (int ti = 0; ti < 16; ++ti) {
    int e = ti & 7;
    if (V == 2) {                          // queue + poff-walk emulation
      if (tid == 0) tS = atomicAdd(dq, 1);
      __syncthreads();
      int r0 = ((tS & 127) << 7) % poff[NEXP];
      e = 0;
      while (r0 >= poff[e + 1]) ++e;
    } else {
      __syncthreads();                     // real kernel's inter-tile sync
    }
    f32x4 acc[4][4] = {};
    STAGE_(Ab, Bb, &As[0][0], &Bs[0][0], 0)
#pragma unroll
    for (int t = 0; t < 16; ++t) {
      if (t < 15) {
        STAGE_(Ab, Bb, &As[(t + 1) & 1][0], &Bs[(t + 1) & 1][0], (t + 1) * 64)
        asm volatile("s_waitcnt vmcnt(8)" ::: "memory");
      } else {
        asm volatile("s_waitcnt vmcnt(0)" ::: "memory");
      }
      __builtin_amdgcn_s_barrier();
      DCOMPUTE(&As[t & 1][0], &Bs[t & 1][0])
      asm volatile("s_waitcnt lgkmcnt(0)" ::: "memory");
      __builtin_amdgcn_s_barrier();
    }

    const int cbase = lane & 15;
    const int rbase = (lane >> 4) * 4;
    const int row0s = (((bid << 4) + ti) & 63) << 7;   // scratch rows < 8192
    if (V == 1) {
      // exact PASS1 epilogue pattern: 64 scalar strided u16 stores/thread
      const float* bb = bias + (e << 10) + (ti & 7) * 128;
#pragma unroll
      for (int ni = 0; ni < 4; ++ni) {
        const int col = wn + ni * 16 + cbase;
        const float bv = bb[col];
#pragma unroll
        for (int mi = 0; mi < 4; ++mi) {
          const int mb = wm + mi * 16 + rbase;
#pragma unroll
          for (int j = 0; j < 4; ++j) {
            float v = fmaxf(acc[mi][ni][j] + bv, 0.0f);
            sink[((size_t)(row0s + mb + j) << 10) + (size_t)((ti & 7) * 128 + col)] = f2bf(v);
          }
        }
      }
    } else if (V == 3) {
      // vectorized epilogue: acc -> LDS (u16 tile) -> coalesced short8 stores
      const float* bb = bias + (e << 10) + (ti & 7) * 128;
      u16* T = &As[0][0];                  // 16384 u16 = 32 KB, dead post-drain
#pragma unroll
      for (int ni = 0; ni < 4; ++ni) {
        const int col = wn + ni * 16 + cbase;
        const float bv = bb[col];
#pragma unroll
        for (int mi = 0; mi < 4; ++mi) {
          const int mb = wm + mi * 16 + rbase;
#pragma unroll
          for (int j = 0; j < 4; ++j)
            T[(mb + j) * 128 + col] = f2bf(fmaxf(acc[mi][ni][j] + bv, 0.0f));
        }
      }
      asm volatile("s_waitcnt lgkmcnt(0)" ::: "memory");
      __builtin_amdgcn_s_barrier();
#pragma unroll
      for (int q = 0; q < 8; ++q) {
        const int idx = q * 2048 + tid * 8;
        short8 v = *(const short8*)&T[idx];
        const int row = idx >> 7, col = idx & 127;
        *(short8*)&sink[((size_t)(row0s + row) << 10) + (size_t)((ti & 7) * 128 + col)] = v;
      }
      asm volatile("s_waitcnt lgkmcnt(0)" ::: "memory");
      __builtin_amdgcn_s_barrier();        // LDS reads done before next STAGE
    } else {
      // V0 / V2: no epilogue; keep acc (and e) alive with one store per tile
      float s = (float)e;
#pragma unroll
      for (int mi = 0; mi < 4; ++mi)
#pragma unroll
        for (int ni = 0; ni < 4; ++ni)
#pragma unroll
          for (int j = 0; j < 4; ++j) s += acc[mi][ni][j];
      sink2[(size_t)bid * 256 + tid] = f2bf(s);
    }
  }
}

// ---- host-side launch ------------------------------------------------------
extern "C" void kernel_launch(void* const* d_in, const int* in_sizes, int n_in,
                              void* d_out, int out_size, void* d_ws, size_t ws_size,
                              hipStream_t stream) {
  (void)in_sizes; (void)n_in; (void)ws_size;
  const float* x  = (const float*)d_in[0];
  const float* W1 = (const float*)d_in[1];
  const float* b1 = (const float*)d_in[2];
  const float* W2 = (const float*)d_in[3];
  const float* b2 = (const float*)d_in[4];
  const float* Wg = (const float*)d_in[5];
  const float* bg = (const float*)d_in[6];
  float* out = (float*)d_out;
  char* ws = (char*)d_ws;

  u16*   W1T   = (u16*)(ws + OFF_W1T);
  u16*   W2T   = (u16*)(ws + OFF_W2T);
  u16*   xp    = (u16*)(ws + OFF_XP);
  u16*   h1    = (u16*)(ws + OFF_H1);
  int*   gidx  = (int*)(ws + OFF_GIDX);
  float* gval  = (float*)(ws + OFF_GVAL);
  int*   ptok  = (int*)(ws + OFF_PTOK);
  float* pgate = (float*)(ws + OFF_PGATE);
  int*   counts = (int*)(ws + OFF_CTRL);
  int*   cursor = counts + 8;
  int*   poff   = counts + 16;   // 9 ints
  int*   qh1    = counts + 25;
  int*   qh2    = counts + 26;
  int*   dq     = counts + 27;

  hipMemsetAsync(d_out, 0, (size_t)out_size * 4, stream);
  hipMemsetAsync(ws + OFF_PTOK, 0, 139392, stream);

  convw_kernel<<<4096, 256, 0, stream>>>(W1, W2, W1T, W2T);
  gate_kernel<<<N_TOK / 4, 256, 0, stream>>>(x, Wg, bg, gidx, gval, counts);
  scan_kernel<<<1, 64, 0, stream>>>(counts, poff);
  scatter_kernel<<<N_TOK / 256, 256, 0, stream>>>(gidx, gval, poff, cursor, ptok, pgate);
  gather_kernel<<<PADROWS / 4, 256, 0, stream>>>(x, ptok, xp);
  gemm_kernel<1><<<MAXRT * 8, 256, 0, stream>>>(xp, W1T, b1, poff, ptok, pgate, h1, nullptr, qh1);
  gemm_kernel<2><<<MAXRT * 8, 256, 0, stream>>>(h1, W2T, b2, poff, ptok, pgate, nullptr, out, qh2);

  // diagnostics (h1 rows < 16384 are fully rewritten by gemm1 every launch,
  // and gemm2's reads precede these writes in stream order -> output-safe)
  u16* dsink  = h1;                                   // rows 0..8191
  u16* dsink2 = h1 + ((size_t)8192 << 10);            // rows 8192..8319
  diag_full<<<512, 256, 0, stream>>>(xp, W1T, xp + 16000000u);
  diagT<0><<<512, 256, 0, stream>>>(xp, W1T, b1, poff, dsink, dsink2, dq);
  diagT<1><<<512, 256, 0, stream>>>(xp, W1T, b1, poff, dsink, dsink2, dq);
  diagT<2><<<512, 256, 0, stream>>>(xp, W1T, b1, poff, dsink, dsink2, dq);
  diagT<3><<<512, 256, 0, stream>>>(xp, W1T, b1, poff, dsink, dsink2, dq);
}

// Round 11
// 335.524 us; speedup vs baseline: 8.1653x; 8.1653x over previous
//
#include <hip/hip_runtime.h>
#include <stdint.h>

// ---- problem constants -----------------------------------------------------
#define N_TOK   8192
#define DIMK    1024      // D == H == 1024
#define NEXP    8
#define PADROWS 17408     // 16384 assignments + up to 8*128 padding, 128-aligned
#define MAXRT   136       // max row tiles of 128

typedef __attribute__((ext_vector_type(8))) short short8;   // 8 bf16 (4 VGPRs)
typedef __attribute__((ext_vector_type(4))) float f32x4;    // MFMA accumulator
typedef unsigned short u16;

__device__ __forceinline__ u16 f2bf(float f) {              // RNE f32->bf16
  uint32_t u = __builtin_bit_cast(uint32_t, f);
  u += 0x7fffu + ((u >> 16) & 1u);
  return (u16)(u >> 16);
}

__device__ __forceinline__ void load16_lds(const void* g, void* l) {
  __builtin_amdgcn_global_load_lds(
      (const __attribute__((address_space(1))) void*)g,
      (__attribute__((address_space(3))) void*)l, 16, 0, 0);
}

// ---- workspace layout (bytes) ----------------------------------------------
#define OFF_W1T   0u
#define OFF_W2T   16777216u
#define OFF_XP    33554432u
#define OFF_H1    69206016u
#define OFF_GIDX  104857600u
#define OFF_GVAL  104923136u
#define OFF_PTOK  104988672u
#define OFF_PGATE 105058304u
#define OFF_CTRL  105127936u
// zero region each launch: ptok + pgate + ctrl = 69632+69632+128 = 139392 B

// ---- W transpose+convert via LDS tile: WT[e][n][k] = bf16(W[e][k][n]) ------
__global__ void convw_kernel(const float* __restrict__ W1, const float* __restrict__ W2,
                             u16* __restrict__ W1T, u16* __restrict__ W2T) {
  __shared__ u16 tile[64][65];
  int b = (int)blockIdx.x;
  const float* src = W1; u16* dst = W1T;
  if (b >= 2048) { src = W2; dst = W2T; b -= 2048; }
  const int e  = b >> 8;
  const int t  = b & 255;
  const int k0 = (t >> 4) << 6;
  const int n0 = (t & 15) << 6;
  const int tid = (int)threadIdx.x;
  const int r  = tid >> 2;
  const int c4 = (tid & 3) << 4;
  const float4* s = (const float4*)(src + ((size_t)e << 20) +
                                    ((size_t)(k0 + r) << 10) + n0 + c4);
#pragma unroll
  for (int j = 0; j < 4; ++j) {
    float4 v = s[j];
    tile[r][c4 + 4 * j + 0] = f2bf(v.x);
    tile[r][c4 + 4 * j + 1] = f2bf(v.y);
    tile[r][c4 + 4 * j + 2] = f2bf(v.z);
    tile[r][c4 + 4 * j + 3] = f2bf(v.w);
  }
  __syncthreads();
  const int on = tid >> 2;
  const int ok = (tid & 3) << 4;
  u16* d = dst + ((size_t)e << 20) + ((size_t)(n0 + on) << 10) + k0 + ok;
  short8 v0, v1;
#pragma unroll
  for (int j = 0; j < 8; ++j) {
    v0[j] = (short)tile[ok + j][on];
    v1[j] = (short)tile[ok + 8 + j][on];
  }
  *(short8*)d = v0;
  *(short8*)(d + 8) = v1;
}

// ---- gating: f32 logits, top-2 (jax tie-break), softmax, histogram ---------
__global__ void gate_kernel(const float* __restrict__ x, const float* __restrict__ Wg,
                            const float* __restrict__ bg, int* __restrict__ gidx,
                            float* __restrict__ gval, int* __restrict__ counts) {
  __shared__ int hist[NEXP];
  const int tid = (int)threadIdx.x;
  if (tid < NEXP) hist[tid] = 0;
  __syncthreads();
  const int n = (int)blockIdx.x * 4 + (tid >> 6);
  const int lane = tid & 63;
  float acc[NEXP];
#pragma unroll
  for (int e = 0; e < NEXP; ++e) acc[e] = 0.f;
  const float4* xr = (const float4*)(x + ((size_t)n << 10));
#pragma unroll
  for (int j = 0; j < 4; ++j) {
    float4 xv = xr[j * 64 + lane];
#pragma unroll
    for (int e = 0; e < NEXP; ++e) {
      float4 wv = ((const float4*)(Wg + ((size_t)e << 10)))[j * 64 + lane];
      acc[e] += xv.x * wv.x + xv.y * wv.y + xv.z * wv.z + xv.w * wv.w;
    }
  }
#pragma unroll
  for (int e = 0; e < NEXP; ++e)
#pragma unroll
    for (int off = 32; off; off >>= 1) acc[e] += __shfl_xor(acc[e], off, 64);
  if (lane == 0) {
    float lg[NEXP];
#pragma unroll
    for (int e = 0; e < NEXP; ++e) lg[e] = acc[e] + bg[e];
    int e0 = 0; float v0 = lg[0];
#pragma unroll
    for (int e = 1; e < NEXP; ++e) if (lg[e] > v0) { v0 = lg[e]; e0 = e; }
    int e1 = -1; float v1 = -1e30f;
#pragma unroll
    for (int e = 0; e < NEXP; ++e) if (e != e0 && lg[e] > v1) { v1 = lg[e]; e1 = e; }
    float t = expf(v1 - v0);            // v0 >= v1
    float g0 = 1.f / (1.f + t);
    gidx[2 * n] = e0; gidx[2 * n + 1] = e1;
    gval[2 * n] = g0; gval[2 * n + 1] = t * g0;
    atomicAdd(&hist[e0], 1); atomicAdd(&hist[e1], 1);
  }
  __syncthreads();
  if (tid < NEXP && hist[tid]) atomicAdd(&counts[tid], hist[tid]);
}

// ---- scan: 128-aligned segment offsets -------------------------------------
__global__ void scan_kernel(const int* __restrict__ counts, int* __restrict__ poff) {
  if (threadIdx.x == 0) {
    int off = 0; poff[0] = 0;
    for (int e = 0; e < NEXP; ++e) { off += ((counts[e] + 127) >> 7) << 7; poff[e + 1] = off; }
  }
}

// ---- scatter assignments into expert segments ------------------------------
__global__ void scatter_kernel(const int* __restrict__ gidx, const float* __restrict__ gval,
                               const int* __restrict__ poff, int* __restrict__ cursor,
                               int* __restrict__ ptok, float* __restrict__ pgate) {
  const int n = (int)blockIdx.x * 256 + (int)threadIdx.x;
#pragma unroll
  for (int k = 0; k < 2; ++k) {
    const int e = gidx[2 * n + k];
    const int p = poff[e] + atomicAdd(&cursor[e], 1);
    ptok[p] = n;
    pgate[p] = gval[2 * n + k];
  }
}

// ---- gather x rows (permuted) -> bf16 --------------------------------------
__global__ void gather_kernel(const float* __restrict__ x, const int* __restrict__ ptok,
                              u16* __restrict__ xp) {
  const int p = (int)blockIdx.x * 4 + ((int)threadIdx.x >> 6);
  const int lane = (int)threadIdx.x & 63;
  const int tok = ptok[p];
  const float4* src = (const float4*)(x + ((size_t)tok << 10));
  ushort4* dst = (ushort4*)(xp + ((size_t)p << 10));
#pragma unroll
  for (int j = 0; j < 4; ++j) {
    float4 v = src[j * 64 + lane];
    ushort4 o; o.x = f2bf(v.x); o.y = f2bf(v.y); o.z = f2bf(v.z); o.w = f2bf(v.w);
    dst[j * 64 + lane] = o;
  }
}

// ---- grouped GEMM: CROSS-TILE CONTINUOUS PIPELINE ---------------------------
// Evidence: the identical K-step code runs at 1165 TF when continuous
// (diag_full) vs 302 TF in the per-tile-restart kernel. This version never
// drains: step 15 of tile n stages tile n+1's slab 0 (bases from a claim made
// at step 8, published at step 14). Epilogue overlaps slab-0's flight.
// vmcnt audit (per wave): steady step t: outstanding = slab(t)(8)+slab(t+1)(8)
//   -> vmcnt(8) retires slab(t). Step 15: toks(2, issued pre-STAGE)+slab0(8)
//   -> vmcnt(8) retires step14 slab + toks. Step 0: slab0(8)+epilogue
//   stores/atomics+slab1(8) -> vmcnt(16) retires slab0 (+older stores).
// Pass-1 epilogue: acc -> LDS scratch (stride 136 u16: 16B-aligned rows,
// 4-way max bank groups) -> 256B-contiguous short8 stores = full lines,
// no L2 write-allocate fetch. Scratch overlays buf1 (free at epilogue time;
// buf0 holds in-flight next-slab0 loads).
template <int PASS>
__global__ __launch_bounds__(256, 2)
void gemm_kernel(const u16* __restrict__ A, const u16* __restrict__ WT,
                 const float* __restrict__ bias, const int* __restrict__ poff,
                 const int* __restrict__ ptok, const float* __restrict__ pgate,
                 u16* __restrict__ Hout, float* __restrict__ Out,
                 int* __restrict__ qhead) {
  __shared__ u16 LDS[33792];          // As0|Bs0|As1|Bs1 ; scratch overlays buf1
  __shared__ int tokS[2][128];
  __shared__ float gateS[2][128];
  __shared__ int tileShare;

  u16* const As0 = &LDS[0];
  u16* const Bs0 = &LDS[8192];
  u16* const As1 = &LDS[16384];
  u16* const Bs1 = &LDS[24576];
  u16* const scratch = &LDS[16384];   // 128 rows x 136 u16 = 17408 <= 17408 ok

  const int tid = (int)threadIdx.x;
  const int lane = tid & 63;
  const int wid = tid >> 6;
  const int wm = (wid >> 1) * 64;
  const int wn = (wid & 1) * 64;
  const int r_in = lane >> 3;
  const int s_phys = lane & 7;
  const int cbase = lane & 15;
  const int rbase = (lane >> 4) * 4;

  const int total = (poff[NEXP] >> 7) * 8;

#define STAGE(ADST, BDST, ABASE, BBASE, K0)                                    \
  {                                                                            \
    _Pragma("unroll")                                                          \
    for (int i_ = 0; i_ < 4; ++i_) {                                           \
      const int chunk_ = wid * 4 + i_;                                         \
      const int row_ = chunk_ * 8 + r_in;                                      \
      const int slotL_ = s_phys ^ (row_ & 7);                                  \
      const size_t goff_ = ((size_t)row_ << 10) + (size_t)((K0) + slotL_ * 8); \
      load16_lds((ABASE) + goff_, (ADST) + chunk_ * 512);                      \
      load16_lds((BBASE) + goff_, (BDST) + chunk_ * 512);                      \
    }                                                                          \
  }

#define COMPUTE(ASRC, BSRC)                                                    \
  {                                                                            \
    _Pragma("unroll")                                                          \
    for (int kk = 0; kk < 2; ++kk) {                                           \
      short8 af[4], bf_[4];                                                    \
      const int kslot = kk * 4 + (lane >> 4);                                  \
      _Pragma("unroll")                                                        \
      for (int mi = 0; mi < 4; ++mi) {                                         \
        const int m = wm + mi * 16 + cbase;                                    \
        af[mi] = *(const short8*)((const char*)(ASRC) + m * 128 +              \
                                  ((kslot ^ (m & 7)) << 4));                   \
      }                                                                        \
      _Pragma("unroll")                                                        \
      for (int ni = 0; ni < 4; ++ni) {                                         \
        const int n = wn + ni * 16 + cbase;                                    \
        bf_[ni] = *(const short8*)((const char*)(BSRC) + n * 128 +             \
                                   ((kslot ^ (n & 7)) << 4));                  \
      }                                                                        \
      _Pragma("unroll")                                                        \
      for (int mi = 0; mi < 4; ++mi)                                           \
        _Pragma("unroll")                                                      \
        for (int ni = 0; ni < 4; ++ni)                                         \
          acc[mi][ni] = __builtin_amdgcn_mfma_f32_16x16x32_bf16(               \
              af[mi], bf_[ni], acc[mi][ni], 0, 0, 0);                          \
    }                                                                          \
  }

  // ---- prologue: first claim + slab 0, one-time full drain ----
  if (tid == 0) tileShare = atomicAdd(qhead, 1);
  __syncthreads();
  int tile = tileShare;
  if (tile >= total) return;
  int par = 0;
  int ct = tile & 7;
  int row0 = (tile >> 3) << 7;
  int e = 0;
  while (row0 >= poff[e + 1]) ++e;
  const u16* Ab = A + ((size_t)row0 << 10);
  const u16* Bb = WT + ((size_t)e << 20) + ((size_t)(ct * 128) << 10);
  if (PASS == 2) {
    const int q = tid & 127;
    tokS[0][q] = ptok[row0 + q];
    gateS[0][q] = pgate[row0 + q];
  }
  STAGE(As0, Bs0, Ab, Bb, 0)
  asm volatile("s_waitcnt vmcnt(0)" ::: "memory");
  __builtin_amdgcn_s_barrier();

  int nextT = 0;
  for (;;) {                                   // one iteration per tile
    f32x4 acc[4][4] = {};

    // step 0: stage slab1 -> buf1; vmcnt(16) accounts epilogue stores in flight
    STAGE(As1, Bs1, Ab, Bb, 64)
    asm volatile("s_waitcnt vmcnt(16)" ::: "memory");
    __builtin_amdgcn_s_barrier();
    COMPUTE(As0, Bs0)
    asm volatile("s_waitcnt lgkmcnt(0)" ::: "memory");
    __builtin_amdgcn_s_barrier();

    // steps 1..14 (t odd stages buf0, computes buf1; t even vice versa)
#pragma unroll
    for (int t = 1; t < 15; ++t) {
      if (t == 8) { if (tid == 0) nextT = atomicAdd(qhead, 1); }
      if (t & 1) { STAGE(As0, Bs0, Ab, Bb, (t + 1) * 64) }
      else       { STAGE(As1, Bs1, Ab, Bb, (t + 1) * 64) }
      asm volatile("s_waitcnt vmcnt(8)" ::: "memory");
      __builtin_amdgcn_s_barrier();
      if (t & 1) { COMPUTE(As1, Bs1) }
      else       { COMPUTE(As0, Bs0) }
      if (t == 14) { if (tid == 0) tileShare = nextT; }   // publish claim
      asm volatile("s_waitcnt lgkmcnt(0)" ::: "memory");
      __builtin_amdgcn_s_barrier();
    }

    // step 15: stage NEXT tile's slab 0 -> buf0 (rhythm unbroken)
    const int nt = tileShare;                  // visible since t14 barrier
    const bool valid = nt < total;
    const int tU = valid ? nt : tile;          // fallback: restage current (unused)
    const int ctN = tU & 7;
    const int row0N = (tU >> 3) << 7;
    int eN = 0;
    while (row0N >= poff[eN + 1]) ++eN;
    const u16* AbN = A + ((size_t)row0N << 10);
    const u16* BbN = WT + ((size_t)eN << 20) + ((size_t)(ctN * 128) << 10);
    if (PASS == 2) {                           // all waves: uniform +2 vmcnt
      const int q = tid & 127;
      tokS[par ^ 1][q] = ptok[row0N + q];
      gateS[par ^ 1][q] = pgate[row0N + q];
    }
    STAGE(As0, Bs0, AbN, BbN, 0)
    asm volatile("s_waitcnt vmcnt(8)" ::: "memory");   // step14 slab + toks in
    __builtin_amdgcn_s_barrier();
    COMPUTE(As1, Bs1)
    asm volatile("s_waitcnt lgkmcnt(0)" ::: "memory");
    __builtin_amdgcn_s_barrier();

    // ---- epilogue for CURRENT tile (overlaps next slab0 flight) ----
    const float* bb = bias + (e << 10) + ct * 128;
    if (PASS == 1) {
      // acc -> scratch (buf1 region, free now; stride 136 u16)
#pragma unroll
      for (int ni = 0; ni < 4; ++ni) {
        const int col = wn + ni * 16 + cbase;
        const float bv = bb[col];
#pragma unroll
        for (int mi = 0; mi < 4; ++mi) {
          const int mb = wm + mi * 16 + rbase;
#pragma unroll
          for (int j = 0; j < 4; ++j)
            scratch[(mb + j) * 136 + col] = f2bf(fmaxf(acc[mi][ni][j] + bv, 0.0f));
        }
      }
      asm volatile("s_waitcnt lgkmcnt(0)" ::: "memory");
      __builtin_amdgcn_s_barrier();
      // coalesced full-line stores: 16 lanes x 16B = 256B per row segment
#pragma unroll
      for (int q = 0; q < 8; ++q) {
        const int idx = q * 2048 + tid * 8;
        const int row = idx >> 7, colq = idx & 127;
        short8 v = *(const short8*)&scratch[row * 136 + colq];
        *(short8*)&Hout[((size_t)(row0 + row) << 10) + (size_t)(ct * 128 + colq)] = v;
      }
      asm volatile("s_waitcnt lgkmcnt(0)" ::: "memory");
      __builtin_amdgcn_s_barrier();            // scratch reads done before next
    } else {                                   // step-0 STAGE rewrites buf1
#pragma unroll
      for (int ni = 0; ni < 4; ++ni) {
        const int col = wn + ni * 16 + cbase;
        const float bv = bb[col];
#pragma unroll
        for (int mi = 0; mi < 4; ++mi) {
          const int mb = wm + mi * 16 + rbase;
#pragma unroll
          for (int j = 0; j < 4; ++j) {
            const int m = mb + j;              // pad rows: gate==0 -> +0 exactly
            float v = fmaxf(acc[mi][ni][j] + bv, 0.0f);
            unsafeAtomicAdd(Out + ((size_t)tokS[par][m] << 10) + (size_t)(ct * 128 + col),
                            v * gateS[par][m]);
          }
        }
      }
    }

    if (!valid) break;
    tile = tU; ct = ctN; row0 = row0N; e = eN; Ab = AbN; Bb = BbN; par ^= 1;
  }
#undef STAGE
#undef COMPUTE
}

// ---- host-side launch ------------------------------------------------------
extern "C" void kernel_launch(void* const* d_in, const int* in_sizes, int n_in,
                              void* d_out, int out_size, void* d_ws, size_t ws_size,
                              hipStream_t stream) {
  (void)in_sizes; (void)n_in; (void)ws_size;
  const float* x  = (const float*)d_in[0];
  const float* W1 = (const float*)d_in[1];
  const float* b1 = (const float*)d_in[2];
  const float* W2 = (const float*)d_in[3];
  const float* b2 = (const float*)d_in[4];
  const float* Wg = (const float*)d_in[5];
  const float* bg = (const float*)d_in[6];
  float* out = (float*)d_out;
  char* ws = (char*)d_ws;

  u16*   W1T   = (u16*)(ws + OFF_W1T);
  u16*   W2T   = (u16*)(ws + OFF_W2T);
  u16*   xp    = (u16*)(ws + OFF_XP);
  u16*   h1    = (u16*)(ws + OFF_H1);
  int*   gidx  = (int*)(ws + OFF_GIDX);
  float* gval  = (float*)(ws + OFF_GVAL);
  int*   ptok  = (int*)(ws + OFF_PTOK);
  float* pgate = (float*)(ws + OFF_PGATE);
  int*   counts = (int*)(ws + OFF_CTRL);
  int*   cursor = counts + 8;
  int*   poff   = counts + 16;   // 9 ints
  int*   qh1    = counts + 25;
  int*   qh2    = counts + 26;

  hipMemsetAsync(d_out, 0, (size_t)out_size * 4, stream);
  hipMemsetAsync(ws + OFF_PTOK, 0, 139392, stream);

  convw_kernel<<<4096, 256, 0, stream>>>(W1, W2, W1T, W2T);
  gate_kernel<<<N_TOK / 4, 256, 0, stream>>>(x, Wg, bg, gidx, gval, counts);
  scan_kernel<<<1, 64, 0, stream>>>(counts, poff);
  scatter_kernel<<<N_TOK / 256, 256, 0, stream>>>(gidx, gval, poff, cursor, ptok, pgate);
  gather_kernel<<<PADROWS / 4, 256, 0, stream>>>(x, ptok, xp);
  gemm_kernel<1><<<512, 256, 0, stream>>>(xp, W1T, b1, poff, ptok, pgate, h1, nullptr, qh1);
  gemm_kernel<2><<<512, 256, 0, stream>>>(h1, W2T, b2, poff, ptok, pgate, nullptr, out, qh2);
}